// Round 3
// baseline (745.329 us; speedup 1.0000x reference)
//
#include <hip/hip_runtime.h>
#include <math.h>

// B=64 T=50 V=32000 E=64 DH=128 H=8 M=256 ; rows R = B*T = 3200
// Float tensors are f32; x is int32. Split-bf16 (hi+lo) MFMA GEMMs, LDS-free.
#define T_ 50
#define R_ 3200

using u16 = unsigned short;
typedef __attribute__((ext_vector_type(8))) __bf16 bf16x8;
typedef __attribute__((ext_vector_type(4))) float f32x4;

__device__ __forceinline__ float bf2f(u16 u) {
  union { unsigned int i; float f; } x; x.i = ((unsigned int)u) << 16; return x.f;
}
__device__ __forceinline__ u16 f2bf(float f) {
  union { float f; unsigned int i; } x; x.f = f;
  unsigned int r = x.i + 0x7FFFu + ((x.i >> 16) & 1u);  // RNE
  return (u16)(r >> 16);
}
__device__ __forceinline__ void split2(float v, u16& hi, u16& lo) {
  hi = f2bf(v);
  lo = f2bf(v - bf2f(hi));
}
__device__ __forceinline__ float gelu_f(float v) {
  return 0.5f * v * (1.0f + erff(v * 0.70710678118654752f));
}

// ---------------- prep: embed + pack + transpose, one kernel ----------------
// blocks [0,800): embed h=tok[x]+pos -> split hh/hl [3200][64]
// blocks [800,1964): pack WqkvT/bqkv/WoT/W1T/W2T (split)
// blocks [1964,2464): transpose Wf -> WfT split [32000][64]
__global__ __launch_bounds__(256) void k_prep(
    const int* __restrict__ x, const float* __restrict__ tok, const float* __restrict__ pos,
    const float* __restrict__ Wq, const float* __restrict__ Wk, const float* __restrict__ Wv,
    const float* __restrict__ bq, const float* __restrict__ bk, const float* __restrict__ bv,
    const float* __restrict__ Wo, const float* __restrict__ W1, const float* __restrict__ W2,
    const float* __restrict__ Wf,
    u16* __restrict__ hh, u16* __restrict__ hl,
    u16* __restrict__ WqkvTh, u16* __restrict__ WqkvTl, float* __restrict__ bqkv,
    u16* __restrict__ WoTh, u16* __restrict__ WoTl,
    u16* __restrict__ W1Th, u16* __restrict__ W1Tl,
    u16* __restrict__ W2Th, u16* __restrict__ W2Tl,
    u16* __restrict__ WfTh, u16* __restrict__ WfTl) {
  __shared__ __align__(16) float tile[64][68];
  int blk = blockIdx.x;
  if (blk < 800) {
    int i = blk * 256 + threadIdx.x;
    int row = i >> 6, e = i & 63;
    int t = row % T_;
    split2(tok[(long)x[row] * 64 + e] + pos[t * 64 + e], hh[i], hl[i]);
    return;
  }
  if (blk < 1964) {
    int i = (blk - 800) * 256 + threadIdx.x;
    const int S0 = 196608, S1 = 3072, S2 = 65536, S3 = 16384;
    if (i < S0) {
      int n = i >> 6, e = i & 63;
      int p = n >> 10, rem = n & 1023;
      int hh2 = rem >> 7, d = rem & 127;
      const float* W = (p == 0) ? Wq : ((p == 1) ? Wk : Wv);
      split2(W[hh2 * 8192 + e * 128 + d], WqkvTh[i], WqkvTl[i]);
      return;
    }
    i -= S0;
    if (i < S1) { int p = i >> 10, rem = i & 1023;
      const float* bb = (p == 0) ? bq : ((p == 1) ? bk : bv);
      bqkv[i] = bb[rem]; return; }
    i -= S1;
    if (i < S2) { int n = i >> 10, k = i & 1023;
      split2(Wo[k * 64 + n], WoTh[i], WoTl[i]); return; }
    i -= S2;
    if (i < S3) { int n = i >> 6, k = i & 63;
      split2(W1[k * 256 + n], W1Th[i], W1Tl[i]); return; }
    i -= S3;
    if (i < S3) { int n = i >> 8, k = i & 255;
      split2(W2[k * 64 + n], W2Th[i], W2Tl[i]); }
    return;
  }
  // transpose Wf tile
  int n0 = (blk - 1964) * 64;
  for (int c = threadIdx.x; c < 1024; c += 256) {
    int k = c >> 4, ch = (c & 15) * 4;
    *(float4*)&tile[k][ch] = *(const float4*)&Wf[(long)k * 32000 + n0 + ch];
  }
  __syncthreads();
  for (int c = threadIdx.x; c < 1024; c += 256) {
    int n = c >> 4, ch = (c & 15) * 4;
    u16 th[4], tl[4];
#pragma unroll
    for (int j = 0; j < 4; ++j) split2(tile[ch + j][n], th[j], tl[j]);
    *(ushort4*)&WfTh[(long)(n0 + n) * 64 + ch] = *(ushort4*)th;
    *(ushort4*)&WfTl[(long)(n0 + n) * 64 + ch] = *(ushort4*)tl;
  }
}

// -------- LDS-free split-bf16 MFMA GEMM: C = A @ Bt^T + bias ---------------
// A pre-split hi/lo, K-major [M][K]; Bt pre-split [N][K]; BM=64 (4 waves x 16
// rows), BN=TN*16. D = ah*bh + al*bh + ah*bl. 16x16x32 frags loaded straight
// from global: each dwordx4 inst covers 16 rows x 64 B -> fully coalesced.
// No LDS, no barriers.
template <int TN, int ACT, int SPLIT>
__global__ __launch_bounds__(256) void k_gemm_rr(
    const u16* __restrict__ Ah, const u16* __restrict__ Al,
    const u16* __restrict__ Bh, const u16* __restrict__ Bl,
    const float* __restrict__ bias, float* __restrict__ Cf,
    u16* __restrict__ Ch, u16* __restrict__ Cl, int ldc, int K) {
  const int m0 = blockIdx.x * 64;
  const int n0 = blockIdx.y * (TN * 16);
  const int lane = threadIdx.x & 63, wave = threadIdx.x >> 6;
  const int ln = lane & 15, quad = lane >> 4;
  const int wm = wave * 16;
  f32x4 acc[TN];
#pragma unroll
  for (int tn = 0; tn < TN; ++tn)
#pragma unroll
    for (int i = 0; i < 4; ++i) acc[tn][i] = 0.f;

  const long arow = (long)(m0 + wm + ln) * K;
  for (int kk = 0; kk < K; kk += 64) {
    const long ab = arow + kk + quad * 8;
    bf16x8 a0h = *(const bf16x8*)&Ah[ab];
    bf16x8 a1h = *(const bf16x8*)&Ah[ab + 32];
    bf16x8 a0l = *(const bf16x8*)&Al[ab];
    bf16x8 a1l = *(const bf16x8*)&Al[ab + 32];
#pragma unroll
    for (int tn = 0; tn < TN; ++tn) {
      const long bb = (long)(n0 + tn * 16 + ln) * K + kk + quad * 8;
      bf16x8 b0h = *(const bf16x8*)&Bh[bb];
      bf16x8 b1h = *(const bf16x8*)&Bh[bb + 32];
      bf16x8 b0l = *(const bf16x8*)&Bl[bb];
      bf16x8 b1l = *(const bf16x8*)&Bl[bb + 32];
      acc[tn] = __builtin_amdgcn_mfma_f32_16x16x32_bf16(a0h, b0h, acc[tn], 0, 0, 0);
      acc[tn] = __builtin_amdgcn_mfma_f32_16x16x32_bf16(a0l, b0h, acc[tn], 0, 0, 0);
      acc[tn] = __builtin_amdgcn_mfma_f32_16x16x32_bf16(a0h, b0l, acc[tn], 0, 0, 0);
      acc[tn] = __builtin_amdgcn_mfma_f32_16x16x32_bf16(a1h, b1h, acc[tn], 0, 0, 0);
      acc[tn] = __builtin_amdgcn_mfma_f32_16x16x32_bf16(a1l, b1h, acc[tn], 0, 0, 0);
      acc[tn] = __builtin_amdgcn_mfma_f32_16x16x32_bf16(a1h, b1l, acc[tn], 0, 0, 0);
    }
  }
  // C/D: col = lane&15, row = quad*4 + reg (verified m89/m91)
#pragma unroll
  for (int tn = 0; tn < TN; ++tn) {
    int col = n0 + tn * 16 + ln;
    float bv = bias[col];
#pragma unroll
    for (int r = 0; r < 4; ++r) {
      long idx = (long)(m0 + wm + quad * 4 + r) * ldc + col;
      float v = acc[tn][r] + bv;
      if (ACT) v = gelu_f(v);
      if (SPLIT) split2(v, Ch[idx], Cl[idx]);
      else Cf[idx] = v;
    }
  }
}

// ---------------- attention: one block per (b,head), fp32 -------------------
// QKV f32 [3200][3072]; lane s holds score[r][s]; K transposed in LDS.
__global__ __launch_bounds__(256) void k_attn(const float* __restrict__ QKV,
                                              u16* __restrict__ Oh,
                                              u16* __restrict__ Ol) {
  __shared__ float KT[128][65];   // banks (d+s)%32: reads 2-way, writes free
  __shared__ __align__(16) float VL[T_][128];
  __shared__ float PL[4][64];
  const int b = blockIdx.x >> 3, hd = blockIdx.x & 7;
  const int tid = threadIdx.x, lane = tid & 63, wave = tid >> 6;
  const float* base = QKV + (long)b * T_ * 3072 + hd * 128;
  for (int c = tid; c < T_ * 128; c += 256) {
    int s = c >> 7, d = c & 127;
    KT[d][s] = base[(long)s * 3072 + 1024 + d];
    VL[s][d] = base[(long)s * 3072 + 2048 + d];
  }
  __syncthreads();
  const float scale = 0.0883883476483184406f;  // 1/sqrt(128)
  for (int r = wave; r < T_; r += 4) {
    const float* qrow = base + (long)r * 3072;
    float ac0 = 0.f, ac1 = 0.f, ac2 = 0.f, ac3 = 0.f;
#pragma unroll 4
    for (int d = 0; d < 128; d += 4) {
      float4 q = *(const float4*)&qrow[d];  // broadcast (uniform addr)
      ac0 += q.x * KT[d][lane];
      ac1 += q.y * KT[d + 1][lane];
      ac2 += q.z * KT[d + 2][lane];
      ac3 += q.w * KT[d + 3][lane];
    }
    float sc = (lane <= r) ? (ac0 + ac1 + ac2 + ac3) * scale : -INFINITY;
    float mx = sc;
    mx = fmaxf(mx, __shfl_xor(mx, 32)); mx = fmaxf(mx, __shfl_xor(mx, 16));
    mx = fmaxf(mx, __shfl_xor(mx, 8));  mx = fmaxf(mx, __shfl_xor(mx, 4));
    mx = fmaxf(mx, __shfl_xor(mx, 2));  mx = fmaxf(mx, __shfl_xor(mx, 1));
    float e = expf(sc - mx);  // masked lanes: exp(-inf)=0
    float sum = e;
    sum += __shfl_xor(sum, 32); sum += __shfl_xor(sum, 16); sum += __shfl_xor(sum, 8);
    sum += __shfl_xor(sum, 4);  sum += __shfl_xor(sum, 2);  sum += __shfl_xor(sum, 1);
    PL[wave][lane] = e / sum;   // sum >= 1
    float o0 = 0.f, o1 = 0.f;
    for (int s = 0; s <= r; ++s) {
      float p = PL[wave][s];    // broadcast
      o0 += p * VL[s][lane];
      o1 += p * VL[s][64 + lane];
    }
    long orow = ((long)b * T_ + r) * 1024 + hd * 128;
    split2(o0, Oh[orow + lane], Ol[orow + lane]);
    split2(o1, Oh[orow + 64 + lane], Ol[orow + 64 + lane]);
  }
}

extern "C" void kernel_launch(void* const* d_in, const int* in_sizes, int n_in,
                              void* d_out, int out_size, void* d_ws, size_t ws_size,
                              hipStream_t stream) {
  const int*   x   = (const int*)d_in[0];
  const float* tok = (const float*)d_in[1];
  const float* pos = (const float*)d_in[2];
  const float* Wq  = (const float*)d_in[3];
  const float* bq  = (const float*)d_in[4];
  const float* Wk  = (const float*)d_in[5];
  const float* bk  = (const float*)d_in[6];
  const float* Wv  = (const float*)d_in[7];
  const float* bv  = (const float*)d_in[8];
  const float* Wo  = (const float*)d_in[9];
  const float* bo  = (const float*)d_in[10];
  const float* W1  = (const float*)d_in[11];
  const float* b1  = (const float*)d_in[12];
  const float* W2  = (const float*)d_in[13];
  const float* b2  = (const float*)d_in[14];
  const float* Wf  = (const float*)d_in[15];
  const float* bfv = (const float*)d_in[16];

  char* ws = (char*)d_ws;
  size_t off = 0;
  auto alloc = [&](size_t bytes) { char* p = ws + off; off += (bytes + 255) & ~(size_t)255; return p; };
  u16*   hh     = (u16*)alloc(409600);
  u16*   hl     = (u16*)alloc(409600);
  float* QKV    = (float*)alloc(39321600);
  u16*   oh     = (u16*)alloc(6553600);
  u16*   ol     = (u16*)alloc(6553600);
  u16*   ah     = (u16*)alloc(409600);
  u16*   al     = (u16*)alloc(409600);
  u16*   mh     = (u16*)alloc(1638400);
  u16*   ml     = (u16*)alloc(1638400);
  u16*   yh     = (u16*)alloc(409600);
  u16*   yl     = (u16*)alloc(409600);
  u16*   WqkvTh = (u16*)alloc(393216);
  u16*   WqkvTl = (u16*)alloc(393216);
  float* bqkv   = (float*)alloc(12288);
  u16*   WoTh   = (u16*)alloc(131072);
  u16*   WoTl   = (u16*)alloc(131072);
  u16*   W1Th   = (u16*)alloc(32768);
  u16*   W1Tl   = (u16*)alloc(32768);
  u16*   W2Th   = (u16*)alloc(32768);
  u16*   W2Tl   = (u16*)alloc(32768);
  u16*   WfTh   = (u16*)alloc(4096000);
  u16*   WfTl   = (u16*)alloc(4096000);
  float* out    = (float*)d_out;

  k_prep<<<dim3(2464), 256, 0, stream>>>(x, tok, pos, Wq, Wk, Wv, bq, bk, bv,
      Wo, W1, W2, Wf, hh, hl, WqkvTh, WqkvTl, bqkv, WoTh, WoTl,
      W1Th, W1Tl, W2Th, W2Tl, WfTh, WfTl);
  // QKV: [3200,64] @ [64,3072] -> f32
  k_gemm_rr<8, 0, 0><<<dim3(50, 24), 256, 0, stream>>>(
      hh, hl, WqkvTh, WqkvTl, bqkv, QKV, nullptr, nullptr, 3072, 64);
  k_attn<<<dim3(512), 256, 0, stream>>>(QKV, oh, ol);
  // Wo: [3200,1024] @ [1024,64] -> split a
  k_gemm_rr<4, 0, 1><<<dim3(50, 1), 256, 0, stream>>>(
      oh, ol, WoTh, WoTl, bo, nullptr, ah, al, 64, 1024);
  // FFN1 + GELU: [3200,64] @ [64,256] -> split m
  k_gemm_rr<8, 1, 1><<<dim3(50, 2), 256, 0, stream>>>(
      ah, al, W1Th, W1Tl, b1, nullptr, mh, ml, 256, 64);
  // FFN2: [3200,256] @ [256,64] -> split y
  k_gemm_rr<4, 0, 1><<<dim3(50, 1), 256, 0, stream>>>(
      mh, ml, W2Th, W2Tl, b2, nullptr, yh, yl, 64, 256);
  // Final: [3200,64] @ [64,32000] -> logits f32 (write-bound ~410 MB)
  k_gemm_rr<8, 0, 0><<<dim3(50, 250), 256, 0, stream>>>(
      yh, yl, WfTh, WfTl, bfv, out, nullptr, nullptr, 32000, 64);
}